// Round 1
// baseline (170.646 us; speedup 1.0000x reference)
//
#include <hip/hip_runtime.h>

// RepeatLayers: variable-length repeat_interleave along axis 0.
// Inputs: d_in[0] = encoder_h float32 [N, D], d_in[1] = repeats int32 [N].
// Output: float32 [total_rows, D], total_rows = sum(repeats) (= out_size / D).
//
// Kernel 1: single-block inclusive scan of repeats -> csum in d_ws (N ints).
// Kernel 2: one block per output row; uniform binary search (searchsorted
//           side='right') on csum to find source row, then float4 row copy.

#define SCAN_THREADS 1024
#define ELEMS_PER_THREAD 8   // SCAN_THREADS * ELEMS_PER_THREAD = 8192 = N

__global__ __launch_bounds__(SCAN_THREADS)
void scan_kernel(const int* __restrict__ repeats, int* __restrict__ csum, int n) {
    __shared__ int tmp[SCAN_THREADS];
    const int t = threadIdx.x;
    const int base = t * ELEMS_PER_THREAD;
    int vals[ELEMS_PER_THREAD];
    int s = 0;
#pragma unroll
    for (int j = 0; j < ELEMS_PER_THREAD; ++j) {
        const int idx = base + j;
        const int v = (idx < n) ? repeats[idx] : 0;
        vals[j] = v;
        s += v;
    }
    tmp[t] = s;
    __syncthreads();
    // Hillis-Steele inclusive scan over the 1024 per-thread sums.
    for (int off = 1; off < SCAN_THREADS; off <<= 1) {
        const int v = (t >= off) ? tmp[t - off] : 0;
        __syncthreads();
        tmp[t] += v;
        __syncthreads();
    }
    int run = tmp[t] - s;  // exclusive prefix for this thread's chunk
#pragma unroll
    for (int j = 0; j < ELEMS_PER_THREAD; ++j) {
        run += vals[j];
        const int idx = base + j;
        if (idx < n) csum[idx] = run;  // inclusive cumsum
    }
}

__global__ __launch_bounds__(256)
void gather_rows_kernel(const float* __restrict__ h,
                        const int* __restrict__ csum,
                        float* __restrict__ out,
                        int n_rows_in, int d4 /* = D/4 */) {
    const int row = blockIdx.x;
    // searchsorted(csum, row, side='right'): smallest i with csum[i] > row.
    // All 256 threads run it redundantly -> wave-uniform, broadcast loads.
    int lo = 0, hi = n_rows_in;
    while (lo < hi) {
        const int mid = (lo + hi) >> 1;
        if (csum[mid] > row) hi = mid; else lo = mid + 1;
    }
    const float4* __restrict__ src = (const float4*)h + (size_t)lo * d4;
    float4* __restrict__ dst = (float4*)out + (size_t)row * d4;
    for (int i = threadIdx.x; i < d4; i += blockDim.x) {
        dst[i] = src[i];
    }
}

extern "C" void kernel_launch(void* const* d_in, const int* in_sizes, int n_in,
                              void* d_out, int out_size, void* d_ws, size_t ws_size,
                              hipStream_t stream) {
    const float* encoder_h = (const float*)d_in[0];
    const int*   repeats   = (const int*)d_in[1];
    float*       out       = (float*)d_out;

    const int n = in_sizes[1];            // 8192 source rows
    const int d = in_sizes[0] / n;        // 1024 features
    const int total_rows = out_size / d;  // sum(repeats)

    int* csum = (int*)d_ws;               // n ints of scratch

    scan_kernel<<<1, SCAN_THREADS, 0, stream>>>(repeats, csum, n);
    gather_rows_kernel<<<total_rows, 256, 0, stream>>>(encoder_h, csum, out,
                                                       n, d / 4);
}

// Round 2
// 160.871 us; speedup vs baseline: 1.0608x; 1.0608x over previous
//
#include <hip/hip_runtime.h>

// RepeatLayers: variable-length repeat_interleave along axis 0.
// Inputs: d_in[0] = encoder_h float32 [N, D], d_in[1] = repeats int32 [N].
// Output: float32 [total_rows, D], total_rows = sum(repeats) (= out_size / D).
//
// R1 change: replace per-output-row binary search (13 dependent global loads,
// latency-bound) with a scattered row-index map built by the scan kernel.
// Gather is then a pure streaming copy with one broadcast idx load per row.
//
// Kernel 1: single-block scan of repeats + scatter idx[p_i + j] = i into d_ws.
// Kernel 2: 4 rows per block, idx loads hoisted for ILP, float4 row copies.

#define SCAN_THREADS 1024
#define ELEMS_PER_THREAD 8   // SCAN_THREADS * ELEMS_PER_THREAD = 8192 = N
#define ROWS_PER_BLOCK 4

__global__ __launch_bounds__(SCAN_THREADS)
void scan_scatter_kernel(const int* __restrict__ repeats,
                         int* __restrict__ idx_map, int n) {
    __shared__ int tmp[SCAN_THREADS];
    const int t = threadIdx.x;
    const int base = t * ELEMS_PER_THREAD;
    int vals[ELEMS_PER_THREAD];
    int s = 0;
#pragma unroll
    for (int j = 0; j < ELEMS_PER_THREAD; ++j) {
        const int idx = base + j;
        const int v = (idx < n) ? repeats[idx] : 0;
        vals[j] = v;
        s += v;
    }
    tmp[t] = s;
    __syncthreads();
    // Hillis-Steele inclusive scan over the 1024 per-thread sums.
    for (int off = 1; off < SCAN_THREADS; off <<= 1) {
        const int v = (t >= off) ? tmp[t - off] : 0;
        __syncthreads();
        tmp[t] += v;
        __syncthreads();
    }
    int run = tmp[t] - s;  // exclusive prefix for this thread's first element
    // Scatter: output rows [run, run + vals[j]) all come from source row base+j.
#pragma unroll
    for (int j = 0; j < ELEMS_PER_THREAD; ++j) {
        const int src_row = base + j;
        const int r = vals[j];
        for (int k = 0; k < r; ++k) {
            idx_map[run + k] = src_row;
        }
        run += r;
    }
}

__global__ __launch_bounds__(256)
void gather_rows_kernel(const float4* __restrict__ h,
                        const int* __restrict__ idx_map,
                        float4* __restrict__ out,
                        int total_rows, int d4 /* = D/4 */) {
    const int row0 = blockIdx.x * ROWS_PER_BLOCK;
    // Hoist the idx loads: independent, overlap their latency.
    int srcs[ROWS_PER_BLOCK];
#pragma unroll
    for (int r = 0; r < ROWS_PER_BLOCK; ++r) {
        const int row = row0 + r;
        srcs[r] = (row < total_rows) ? idx_map[row] : 0;
    }
#pragma unroll
    for (int r = 0; r < ROWS_PER_BLOCK; ++r) {
        const int row = row0 + r;
        if (row >= total_rows) return;  // rows are processed in order
        const float4* __restrict__ src = h + (size_t)srcs[r] * d4;
        float4* __restrict__ dst = out + (size_t)row * d4;
        for (int i = threadIdx.x; i < d4; i += blockDim.x) {
            dst[i] = src[i];
        }
    }
}

extern "C" void kernel_launch(void* const* d_in, const int* in_sizes, int n_in,
                              void* d_out, int out_size, void* d_ws, size_t ws_size,
                              hipStream_t stream) {
    const float* encoder_h = (const float*)d_in[0];
    const int*   repeats   = (const int*)d_in[1];
    float*       out       = (float*)d_out;

    const int n = in_sizes[1];            // 8192 source rows
    const int d = in_sizes[0] / n;        // 1024 features
    const int total_rows = out_size / d;  // sum(repeats)

    int* idx_map = (int*)d_ws;            // total_rows ints of scratch

    scan_scatter_kernel<<<1, SCAN_THREADS, 0, stream>>>(repeats, idx_map, n);

    const int nblocks = (total_rows + ROWS_PER_BLOCK - 1) / ROWS_PER_BLOCK;
    gather_rows_kernel<<<nblocks, 256, 0, stream>>>(
        (const float4*)encoder_h, idx_map, (float4*)out, total_rows, d / 4);
}